// Round 4
// baseline (719.063 us; speedup 1.0000x reference)
//
#include <hip/hip_runtime.h>
#include <cstdint>

// Problem dims (fixed by reference)
#define BB 4
#define SS 2048
#define HH 1024
#define FF 4096
#define MM (BB * SS)   // 8192 tokens

typedef __attribute__((ext_vector_type(8))) short bf16x8;
typedef __attribute__((ext_vector_type(4))) float f32x4;

__device__ __forceinline__ unsigned short f2b(float f) {
  union { float f; unsigned u; } v; v.f = f;
  unsigned r = v.u + 0x7FFFu + ((v.u >> 16) & 1u);   // round-nearest-even
  return (unsigned short)(r >> 16);
}
__device__ __forceinline__ float b2f(unsigned short u) {
  union { unsigned u; float f; } v; v.u = ((unsigned)u) << 16; return v.f;
}

__device__ __forceinline__ void gld16(const void* g, void* l) {
  __builtin_amdgcn_global_load_lds(
      (const __attribute__((address_space(1))) void*)g,
      (__attribute__((address_space(3))) void*)l, 16, 0, 0);
}

// ---------- elementwise fp32 -> bf16 ----------
__global__ __launch_bounds__(256) void conv_f2b_kernel(
    const float* __restrict__ in, unsigned short* __restrict__ out, long n4) {
  long i = (long)blockIdx.x * 256 + threadIdx.x;
  if (i >= n4) return;
  const float4 f = ((const float4*)in)[i];
  ushort4 o;
  o.x = f2b(f.x); o.y = f2b(f.y); o.z = f2b(f.z); o.w = f2b(f.w);
  ((ushort4*)out)[i] = o;
}

// ---------- transpose fp32 [R,C] -> bf16 [C,R] ----------
__global__ __launch_bounds__(256) void transpose_f2b_kernel(
    const float* __restrict__ in, unsigned short* __restrict__ out, int R, int C) {
  __shared__ float t[32][33];
  int bc = blockIdx.x * 32;
  int br = blockIdx.y * 32;
  int x = threadIdx.x;   // 0..31
  int y0 = threadIdx.y;  // 0..7
#pragma unroll
  for (int yy = y0; yy < 32; yy += 8)
    t[yy][x] = in[(long)(br + yy) * C + bc + x];
  __syncthreads();
#pragma unroll
  for (int yy = y0; yy < 32; yy += 8)
    out[(long)(bc + yy) * R + br + x] = f2b(t[x][yy]);
}

// ---------- transpose bf16 [R,C] slice (ld_in given) -> bf16 [C,R] ----------
__global__ __launch_bounds__(256) void transpose_b2b_kernel(
    const unsigned short* __restrict__ in, long ldin,
    unsigned short* __restrict__ out, int R, int C) {
  __shared__ unsigned short t[32][33];
  int bc = blockIdx.x * 32;
  int br = blockIdx.y * 32;
  int x = threadIdx.x;
  int y0 = threadIdx.y;
#pragma unroll
  for (int yy = y0; yy < 32; yy += 8)
    t[yy][x] = in[(long)(br + yy) * ldin + bc + x];
  __syncthreads();
#pragma unroll
  for (int yy = y0; yy < 32; yy += 8)
    out[(long)(bc + yy) * R + br + x] = t[x][yy];
}

// ---------- concat 3 bias vectors [HH] -> [3*HH] ----------
__global__ __launch_bounds__(256) void concat3_kernel(
    const float* __restrict__ a, const float* __restrict__ b,
    const float* __restrict__ c, float* __restrict__ o) {
  int i = blockIdx.x * 256 + threadIdx.x;   // 0..3071
  float v = (i < HH) ? a[i] : (i < 2 * HH) ? b[i - HH] : c[i - 2 * HH];
  o[i] = v;
}

// ---------- bf16 MFMA GEMM: C[M,N] = A[M,K] * B[N,K]^T ----------
// 128x128 tile, 4 waves 2x2, each wave 64x64 via 4x4 of 16x16x32 MFMA.
// BK=64 as two BK=32 sub-tiles. LDS layout: per 16-row window (1 KB),
// chunk-major — slot s holds (row s&15, k-chunk s>>4) — so each MFMA
// fragment read is a lane-contiguous 1 KB ds_read_b128 sweep (0 bank
// conflicts, verified round 3), matching the wave-uniform gld16 write
// window exactly.
// Block mapping: plain blockIdx (round-3's XCD swizzle REGRESSED — the
// workgroup->XCD assignment is not id%8; adjacent dispatch ids empirically
// have good L2 adjacency already).
// OUT_MODE: 0 = fp32 out, 1 = bf16 out, 2 = fp32 out + bf16 secondary (C2)
template <int OUT_MODE, int RELU, int HAS_BIAS, int HAS_RES>
__device__ __forceinline__ void gemm_bt_body(
    const unsigned short* __restrict__ A, long lda, long sA,
    const unsigned short* __restrict__ Bm, long ldb, long sB,
    void* __restrict__ Cm, long ldc, long sC,
    unsigned short* __restrict__ C2,
    const float* __restrict__ bias,
    const float* __restrict__ res, long ldr,
    float scale, int K) {
  __shared__ unsigned short As[2 * 128 * 32];   // [sub-tile 0 | sub-tile 1]
  __shared__ unsigned short Bs[2 * 128 * 32];
  const int tid = threadIdx.x;
  const int lane = tid & 63;
  const int wave = tid >> 6;
  const long bm = (long)blockIdx.y * 128;
  const long bn = (long)blockIdx.x * 128;
  const int z = blockIdx.z;

  // staging thread map: thread t sources (row = 16*(t>>6) + (t&15),
  // k-chunk = (t>>4)&3) so gld16's lane-order LDS write yields the
  // chunk-major window layout.
  const long srow = ((tid >> 6) * 16) + (tid & 15);
  const long scol = ((tid >> 4) & 3) * 8;
  const unsigned short* Ap = A + (long)z * sA + (bm + srow) * lda + scol;
  const unsigned short* Bp = Bm + (long)z * sB + (bn + srow) * ldb + scol;
  unsigned short* asd = As + tid * 8;
  unsigned short* bsd = Bs + tid * 8;
  const long a64 = 64 * lda;
  const long b64 = 64 * ldb;

  f32x4 acc[4][4];
#pragma unroll
  for (int i = 0; i < 4; ++i)
#pragma unroll
    for (int j = 0; j < 4; ++j) acc[i][j] = (f32x4){0.f, 0.f, 0.f, 0.f};

  const int mo = (wave >> 1) * 64;
  const int no = (wave & 1) * 64;
  const int aw0 = (mo >> 4) * 512;   // first window base (elements) for A frags
  const int bw0 = (no >> 4) * 512;

  for (int k0 = 0; k0 < K; k0 += 64) {
    __syncthreads();
    // sub-tile 0: k-cols [k0, k0+32)
    gld16(Ap + k0, asd);
    gld16(Ap + a64 + k0, asd + 2048);
    gld16(Bp + k0, bsd);
    gld16(Bp + b64 + k0, bsd + 2048);
    // sub-tile 1: k-cols [k0+32, k0+64)
    gld16(Ap + k0 + 32, asd + 4096);
    gld16(Ap + a64 + k0 + 32, asd + 6144);
    gld16(Bp + k0 + 32, bsd + 4096);
    gld16(Bp + b64 + k0 + 32, bsd + 6144);
    __syncthreads();
#pragma unroll
    for (int ks = 0; ks < 2; ++ks) {
      bf16x8 af[4], bfr[4];
#pragma unroll
      for (int i = 0; i < 4; ++i)
        af[i] = *(const bf16x8*)&As[ks * 4096 + aw0 + i * 512 + lane * 8];
#pragma unroll
      for (int i = 0; i < 4; ++i)
        bfr[i] = *(const bf16x8*)&Bs[ks * 4096 + bw0 + i * 512 + lane * 8];
#pragma unroll
      for (int mi = 0; mi < 4; ++mi)
#pragma unroll
        for (int ni = 0; ni < 4; ++ni)
          acc[mi][ni] = __builtin_amdgcn_mfma_f32_16x16x32_bf16(af[mi], bfr[ni], acc[mi][ni], 0, 0, 0);
    }
  }

  // epilogue: C/D layout col=lane&15, row=(lane>>4)*4+reg (m89-verified)
  const long crow = bm + mo + ((lane >> 4) * 4);
  const long ccol = bn + no + (lane & 15);
#pragma unroll
  for (int mi = 0; mi < 4; ++mi) {
#pragma unroll
    for (int ni = 0; ni < 4; ++ni) {
      const long col = ccol + ni * 16;
      const float bv = HAS_BIAS ? bias[col] : 0.f;
#pragma unroll
      for (int r = 0; r < 4; ++r) {
        const long row = crow + mi * 16 + r;
        float v = acc[mi][ni][r] * scale + bv;
        if (HAS_RES) v += res[row * ldr + col];
        if (RELU) v = fmaxf(v, 0.f);
        const long idx = (long)z * sC + row * ldc + col;
        if (OUT_MODE == 0 || OUT_MODE == 2) ((float*)Cm)[idx] = v;
        if (OUT_MODE == 1) ((unsigned short*)Cm)[idx] = f2b(v);
        if (OUT_MODE == 2) C2[idx] = f2b(v);
      }
    }
  }
}

#define GEMM_KERNEL(NAME, OM, RELU, HB, HR)                                  \
  __global__ __launch_bounds__(256) void NAME(                               \
      const unsigned short* __restrict__ A, long lda, long sA,               \
      const unsigned short* __restrict__ Bm, long ldb, long sB,              \
      void* __restrict__ Cm, long ldc, long sC,                              \
      unsigned short* __restrict__ C2, const float* __restrict__ bias,       \
      const float* __restrict__ res, long ldr, float scale, int K) {         \
    gemm_bt_body<OM, RELU, HB, HR>(A, lda, sA, Bm, ldb, sB, Cm, ldc, sC,     \
                                   C2, bias, res, ldr, scale, K);            \
  }
GEMM_KERNEL(gemm_qkv,  1, 0, 1, 0)
GEMM_KERNEL(gemm_qk,   1, 0, 0, 1)   // bf16 scores, mask fused as residual
GEMM_KERNEL(gemm_av,   2, 0, 0, 0)
GEMM_KERNEL(gemm_ffn1, 1, 1, 1, 0)
GEMM_KERNEL(gemm_ffn2, 0, 0, 1, 1)

// ---------- row softmax over S, bf16 in (mask pre-added) -> bf16 out ----------
__global__ __launch_bounds__(256) void softmax_kernel(
    const unsigned short* __restrict__ Sb, unsigned short* __restrict__ Ab) {
  const long row = blockIdx.x;          // 0..MM-1
  const int tid = threadIdx.x;
  const unsigned short* sr = Sb + row * SS + tid * 8;
  bf16x8 sv = *(const bf16x8*)sr;
  float v[8];
  float mx = -1e30f;
#pragma unroll
  for (int i = 0; i < 8; ++i) {
    v[i] = b2f((unsigned short)sv[i]);
    mx = fmaxf(mx, v[i]);
  }
#pragma unroll
  for (int off = 32; off > 0; off >>= 1) mx = fmaxf(mx, __shfl_xor(mx, off, 64));
  __shared__ float rm[4], rs[4];
  if ((tid & 63) == 0) rm[tid >> 6] = mx;
  __syncthreads();
  mx = fmaxf(fmaxf(rm[0], rm[1]), fmaxf(rm[2], rm[3]));
  float sum = 0.f;
#pragma unroll
  for (int i = 0; i < 8; ++i) { v[i] = __expf(v[i] - mx); sum += v[i]; }
#pragma unroll
  for (int off = 32; off > 0; off >>= 1) sum += __shfl_xor(sum, off, 64);
  if ((tid & 63) == 0) rs[tid >> 6] = sum;
  __syncthreads();
  sum = rs[0] + rs[1] + rs[2] + rs[3];
  const float inv = 1.f / sum;
  bf16x8 ov;
#pragma unroll
  for (int i = 0; i < 8; ++i) ov[i] = (short)f2b(v[i] * inv);
  *(bf16x8*)(Ab + row * SS + tid * 8) = ov;
}

// ---------- in-place LayerNorm over H=1024 ----------
__global__ __launch_bounds__(256) void layernorm_kernel(
    float* __restrict__ Y, const float* __restrict__ g, const float* __restrict__ b) {
  const long row = blockIdx.x;
  float* y = Y + row * HH;
  const int tid = threadIdx.x;
  float v[4];
  float s = 0.f, ss = 0.f;
#pragma unroll
  for (int i = 0; i < 4; ++i) {
    v[i] = y[tid + i * 256];
    s += v[i]; ss += v[i] * v[i];
  }
#pragma unroll
  for (int off = 32; off > 0; off >>= 1) {
    s += __shfl_xor(s, off, 64);
    ss += __shfl_xor(ss, off, 64);
  }
  __shared__ float r1[4], r2[4];
  if ((tid & 63) == 0) { r1[tid >> 6] = s; r2[tid >> 6] = ss; }
  __syncthreads();
  s = r1[0] + r1[1] + r1[2] + r1[3];
  ss = r2[0] + r2[1] + r2[2] + r2[3];
  const float mu = s * (1.f / HH);
  const float var = ss * (1.f / HH) - mu * mu;
  const float rinv = rsqrtf(var + 1e-5f);
#pragma unroll
  for (int i = 0; i < 4; ++i) {
    int c = tid + i * 256;
    y[c] = (v[i] - mu) * rinv * g[c] + b[c];
  }
}

extern "C" void kernel_launch(void* const* d_in, const int* in_sizes, int n_in,
                              void* d_out, int out_size, void* d_ws, size_t ws_size,
                              hipStream_t stream) {
  (void)in_sizes; (void)n_in; (void)out_size; (void)ws_size;
  const float* x     = (const float*)d_in[0];
  const float* mask  = (const float*)d_in[1];
  const float* qW    = (const float*)d_in[2];
  const float* qb    = (const float*)d_in[3];
  const float* kW    = (const float*)d_in[4];
  const float* kb    = (const float*)d_in[5];
  const float* vW    = (const float*)d_in[6];
  const float* vb    = (const float*)d_in[7];
  const float* w1    = (const float*)d_in[8];
  const float* b1    = (const float*)d_in[9];
  const float* w2    = (const float*)d_in[10];
  const float* b2    = (const float*)d_in[11];
  const float* gamma = (const float*)d_in[12];
  const float* beta  = (const float*)d_in[13];
  float* out = (float*)d_out;

  char* ws = (char*)d_ws;
  size_t o = 0;
  auto alloc = [&](size_t bytes) { void* p = ws + o; o += (bytes + 255) & ~(size_t)255; return p; };
  unsigned short* Wqkv = (unsigned short*)alloc((size_t)3 * HH * HH * 2); // [3072][1024] (N,K) bf16
  unsigned short* w1t  = (unsigned short*)alloc((size_t)FF * HH * 2);     // [F][H]
  unsigned short* w2t  = (unsigned short*)alloc((size_t)HH * FF * 2);     // [H][F]
  float*          qkvb = (float*)alloc((size_t)3 * HH * 4);               // concat bias
  unsigned short* xb   = (unsigned short*)alloc((size_t)MM * HH * 2);     // x bf16
  unsigned short* QKVb = (unsigned short*)alloc((size_t)MM * 3 * HH * 2); // [M,3072] bf16
  unsigned short* Vt   = (unsigned short*)alloc((size_t)HH * MM * 2);     // [H][M] V^T bf16
  float*          attnf= (float*)alloc((size_t)MM * HH * 4);              // attn fp32 (residual)
  unsigned short* attnb= (unsigned short*)alloc((size_t)MM * HH * 2);     // attn bf16
  unsigned short* Sb   = (unsigned short*)alloc((size_t)BB * SS * SS * 4);// scores bf16 (over-alloc; tail reused as hb)
  unsigned short* Ab   = (unsigned short*)alloc((size_t)BB * SS * SS * 2);
  unsigned short* hb   = Sb + (size_t)BB * SS * SS;  // [M,F] bf16; Sb dead by FFN1 time

  const dim3 tb(32, 8);

  // 1. x -> bf16
  conv_f2b_kernel<<<MM * HH / 1024, 256, 0, stream>>>(x, xb, (long)MM * HH / 4);
  // 2. weight transposes (fp32 [K,N] -> bf16 [N,K]); QKV concatenated along N
  transpose_f2b_kernel<<<dim3(HH / 32, HH / 32), tb, 0, stream>>>(qW, Wqkv, HH, HH);
  transpose_f2b_kernel<<<dim3(HH / 32, HH / 32), tb, 0, stream>>>(kW, Wqkv + (size_t)HH * HH, HH, HH);
  transpose_f2b_kernel<<<dim3(HH / 32, HH / 32), tb, 0, stream>>>(vW, Wqkv + (size_t)2 * HH * HH, HH, HH);
  transpose_f2b_kernel<<<dim3(FF / 32, HH / 32), tb, 0, stream>>>(w1, w1t, HH, FF);
  transpose_f2b_kernel<<<dim3(HH / 32, FF / 32), tb, 0, stream>>>(w2, w2t, FF, HH);
  concat3_kernel<<<12, 256, 0, stream>>>(qb, kb, vb, qkvb);
  // 3. QKV = x * Wqkv^T + b, single GEMM, bf16 out [M,3072]
  gemm_qkv<<<dim3(3 * HH / 128, MM / 128, 1), 256, 0, stream>>>(
      xb, HH, 0, Wqkv, HH, 0, QKVb, 3 * HH, 0, nullptr, qkvb, nullptr, 0, 1.f, HH);
  // 4. V^T (bf16 [M,1024] slice of QKVb -> bf16 [1024,M])
  transpose_b2b_kernel<<<dim3(HH / 32, MM / 32), tb, 0, stream>>>(
      QKVb + 2 * HH, 3 * HH, Vt, MM, HH);
  // 5. S = Q K^T / sqrt(H) + mask, batched over BB, bf16 out
  gemm_qk<<<dim3(SS / 128, SS / 128, BB), 256, 0, stream>>>(
      QKVb, 3 * HH, (long)SS * 3 * HH, QKVb + HH, 3 * HH, (long)SS * 3 * HH,
      Sb, SS, (long)SS * SS, nullptr, nullptr, mask, SS, 0.03125f, HH);
  // 6. A = softmax(S) -> bf16
  softmax_kernel<<<MM, 256, 0, stream>>>(Sb, Ab);
  // 7. attn = A V, batched; fp32 + bf16 dual output
  gemm_av<<<dim3(HH / 128, SS / 128, BB), 256, 0, stream>>>(
      Ab, SS, (long)SS * SS, Vt, MM, SS, attnf, HH, (long)SS * HH,
      attnb, nullptr, nullptr, 0, 1.f, SS);
  // 8. h = relu(attn w1 + b1) -> bf16
  gemm_ffn1<<<dim3(FF / 128, MM / 128, 1), 256, 0, stream>>>(
      attnb, HH, 0, w1t, HH, 0, hb, FF, 0, nullptr, b1, nullptr, 0, 1.f, HH);
  // 9. y = attn + h w2 + b2 -> fp32 out
  gemm_ffn2<<<dim3(HH / 128, MM / 128, 1), 256, 0, stream>>>(
      hb, FF, 0, w2t, FF, 0, out, HH, 0, nullptr, b2, attnf, HH, 1.f, FF);
  // 10. LayerNorm in place
  layernorm_kernel<<<MM, 256, 0, stream>>>(out, gamma, beta);
}

// Round 6
// 586.634 us; speedup vs baseline: 1.2257x; 1.2257x over previous
//
#include <hip/hip_runtime.h>
#include <cstdint>

// Problem dims (fixed by reference)
#define BB 4
#define SS 2048
#define HH 1024
#define FF 4096
#define MM (BB * SS)   // 8192 tokens

typedef __attribute__((ext_vector_type(8))) short bf16x8;
typedef __attribute__((ext_vector_type(4))) float f32x4;

__device__ __forceinline__ unsigned short f2b(float f) {
  union { float f; unsigned u; } v; v.f = f;
  unsigned r = v.u + 0x7FFFu + ((v.u >> 16) & 1u);   // round-nearest-even
  return (unsigned short)(r >> 16);
}
__device__ __forceinline__ float b2f(unsigned short u) {
  union { unsigned u; float f; } v; v.u = ((unsigned)u) << 16; return v.f;
}

__device__ __forceinline__ void gld16(const void* g, void* l) {
  __builtin_amdgcn_global_load_lds(
      (const __attribute__((address_space(1))) void*)g,
      (__attribute__((address_space(3))) void*)l, 16, 0, 0);
}

// ---------- elementwise fp32 -> bf16 ----------
__global__ __launch_bounds__(256) void conv_f2b_kernel(
    const float* __restrict__ in, unsigned short* __restrict__ out, long n4) {
  long i = (long)blockIdx.x * 256 + threadIdx.x;
  if (i >= n4) return;
  const float4 f = ((const float4*)in)[i];
  ushort4 o;
  o.x = f2b(f.x); o.y = f2b(f.y); o.z = f2b(f.z); o.w = f2b(f.w);
  ((ushort4*)out)[i] = o;
}

// ---------- transpose fp32 [R,C] -> bf16 [C,R] ----------
__global__ __launch_bounds__(256) void transpose_f2b_kernel(
    const float* __restrict__ in, unsigned short* __restrict__ out, int R, int C) {
  __shared__ float t[32][33];
  int bc = blockIdx.x * 32;
  int br = blockIdx.y * 32;
  int x = threadIdx.x;   // 0..31
  int y0 = threadIdx.y;  // 0..7
#pragma unroll
  for (int yy = y0; yy < 32; yy += 8)
    t[yy][x] = in[(long)(br + yy) * C + bc + x];
  __syncthreads();
#pragma unroll
  for (int yy = y0; yy < 32; yy += 8)
    out[(long)(bc + yy) * R + br + x] = f2b(t[x][yy]);
}

// ---------- transpose bf16 [R,C] slice (ld_in given) -> bf16 [C,R] ----------
__global__ __launch_bounds__(256) void transpose_b2b_kernel(
    const unsigned short* __restrict__ in, long ldin,
    unsigned short* __restrict__ out, int R, int C) {
  __shared__ unsigned short t[32][33];
  int bc = blockIdx.x * 32;
  int br = blockIdx.y * 32;
  int x = threadIdx.x;
  int y0 = threadIdx.y;
#pragma unroll
  for (int yy = y0; yy < 32; yy += 8)
    t[yy][x] = in[(long)(br + yy) * ldin + bc + x];
  __syncthreads();
#pragma unroll
  for (int yy = y0; yy < 32; yy += 8)
    out[(long)(bc + yy) * R + br + x] = t[x][yy];
}

// ---------- concat 3 bias vectors [HH] -> [3*HH] ----------
__global__ __launch_bounds__(256) void concat3_kernel(
    const float* __restrict__ a, const float* __restrict__ b,
    const float* __restrict__ c, float* __restrict__ o) {
  int i = blockIdx.x * 256 + threadIdx.x;   // 0..3071
  float v = (i < HH) ? a[i] : (i < 2 * HH) ? b[i - HH] : c[i - 2 * HH];
  o[i] = v;
}

// ---------- bf16 MFMA GEMM: C[M,N] = A[M,K] * B[N,K]^T ----------
// 128x128 tile, 4 waves 2x2, each wave 64x64 via 4x4 of 16x16x32 MFMA.
// BK=64 as two BK=32 sub-tiles.
//
// LDS layout: XOR-swizzled row-major. Sub-tile = 128 rows x 64 B.
// Slot for (row, c_stored) = row*64B + c_stored*16B with
// c_stored = c_global ^ (row & 3).
// - Staging (gld16 forces LDS dest = base + lane*16B): thread t reads global
//   (row = t>>2, chunk = (t&3) ^ ((t>>2)&3)). The XOR permutes only within a
//   row's 64 B segment, so each lane-quad covers one contiguous 64 B segment
//   -> coalescer-ideal (round-2 pattern). [round-3/4's chunk-major map put 16
//   consecutive lanes on 16 rows 8 KB apart -> ~4x TA transactions -> the
//   153 us ffn2 regression]
// - Fragment read: lane l reads (row = l&15, c_stored = (l>>4)^(l&3)); the
//   wave's 64 accesses spread exactly 8 per 16B-bank-group -> conflict-free.
// OUT_MODE: 0 = fp32 out, 1 = bf16 out, 2 = fp32 out + bf16 secondary (C2)
template <int OUT_MODE, int RELU, int HAS_BIAS, int HAS_RES>
__device__ __forceinline__ void gemm_bt_body(
    const unsigned short* __restrict__ A, long lda, long sA,
    const unsigned short* __restrict__ Bm, long ldb, long sB,
    void* __restrict__ Cm, long ldc, long sC,
    unsigned short* __restrict__ C2,
    const float* __restrict__ bias,
    const float* __restrict__ res, long ldr,
    float scale, int K) {
  __shared__ unsigned short As[2 * 128 * 32];   // [sub-tile 0 | sub-tile 1]
  __shared__ unsigned short Bs[2 * 128 * 32];
  const int tid = threadIdx.x;
  const int lane = tid & 63;
  const int wave = tid >> 6;
  const long bm = (long)blockIdx.y * 128;
  const long bn = (long)blockIdx.x * 128;
  const int z = blockIdx.z;

  // staging thread map: row = tid>>2 (quads cover contiguous 64B segments),
  // global chunk = (tid&3) ^ (row&3)  (XOR within the segment).
  const long srow = tid >> 2;                       // 0..63
  const long schunk = (long)((tid & 3) ^ (int)(srow & 3));
  const unsigned short* Ap = A + (long)z * sA + (bm + srow) * lda + schunk * 8;
  const unsigned short* Bp = Bm + (long)z * sB + (bn + srow) * ldb + schunk * 8;
  unsigned short* asd = As + tid * 8;
  unsigned short* bsd = Bs + tid * 8;
  const long a64 = 64 * lda;   // rows 64..127: (64+row)&3 == row&3, same schunk
  const long b64 = 64 * ldb;

  f32x4 acc[4][4];
#pragma unroll
  for (int i = 0; i < 4; ++i)
#pragma unroll
    for (int j = 0; j < 4; ++j) acc[i][j] = (f32x4){0.f, 0.f, 0.f, 0.f};

  const int mo = (wave >> 1) * 64;
  const int no = (wave & 1) * 64;
  const int fr = lane & 15;                       // fragment row within window
  const int fc = ((lane >> 4) ^ (lane & 3)) * 8;  // stored-chunk offset (shorts)

  for (int k0 = 0; k0 < K; k0 += 64) {
    __syncthreads();
    // sub-tile 0: k-cols [k0, k0+32)
    gld16(Ap + k0, asd);
    gld16(Ap + a64 + k0, asd + 2048);
    gld16(Bp + k0, bsd);
    gld16(Bp + b64 + k0, bsd + 2048);
    // sub-tile 1: k-cols [k0+32, k0+64)
    gld16(Ap + k0 + 32, asd + 4096);
    gld16(Ap + a64 + k0 + 32, asd + 6144);
    gld16(Bp + k0 + 32, bsd + 4096);
    gld16(Bp + b64 + k0 + 32, bsd + 6144);
    __syncthreads();
#pragma unroll
    for (int ks = 0; ks < 2; ++ks) {
      bf16x8 af[4], bfr[4];
#pragma unroll
      for (int i = 0; i < 4; ++i)
        af[i] = *(const bf16x8*)&As[ks * 4096 + (mo + i * 16 + fr) * 32 + fc];
#pragma unroll
      for (int i = 0; i < 4; ++i)
        bfr[i] = *(const bf16x8*)&Bs[ks * 4096 + (no + i * 16 + fr) * 32 + fc];
#pragma unroll
      for (int mi = 0; mi < 4; ++mi)
#pragma unroll
        for (int ni = 0; ni < 4; ++ni)
          acc[mi][ni] = __builtin_amdgcn_mfma_f32_16x16x32_bf16(af[mi], bfr[ni], acc[mi][ni], 0, 0, 0);
    }
  }

  // epilogue: C/D layout col=lane&15, row=(lane>>4)*4+reg (m89-verified)
  const long crow = bm + mo + ((lane >> 4) * 4);
  const long ccol = bn + no + (lane & 15);
#pragma unroll
  for (int mi = 0; mi < 4; ++mi) {
#pragma unroll
    for (int ni = 0; ni < 4; ++ni) {
      const long col = ccol + ni * 16;
      const float bv = HAS_BIAS ? bias[col] : 0.f;
#pragma unroll
      for (int r = 0; r < 4; ++r) {
        const long row = crow + mi * 16 + r;
        float v = acc[mi][ni][r] * scale + bv;
        if (HAS_RES) v += res[row * ldr + col];
        if (RELU) v = fmaxf(v, 0.f);
        const long idx = (long)z * sC + row * ldc + col;
        if (OUT_MODE == 0 || OUT_MODE == 2) ((float*)Cm)[idx] = v;
        if (OUT_MODE == 1) ((unsigned short*)Cm)[idx] = f2b(v);
        if (OUT_MODE == 2) C2[idx] = f2b(v);
      }
    }
  }
}

#define GEMM_KERNEL(NAME, OM, RELU, HB, HR)                                  \
  __global__ __launch_bounds__(256) void NAME(                               \
      const unsigned short* __restrict__ A, long lda, long sA,               \
      const unsigned short* __restrict__ Bm, long ldb, long sB,              \
      void* __restrict__ Cm, long ldc, long sC,                              \
      unsigned short* __restrict__ C2, const float* __restrict__ bias,       \
      const float* __restrict__ res, long ldr, float scale, int K) {         \
    gemm_bt_body<OM, RELU, HB, HR>(A, lda, sA, Bm, ldb, sB, Cm, ldc, sC,     \
                                   C2, bias, res, ldr, scale, K);            \
  }
GEMM_KERNEL(gemm_qkv,  1, 0, 1, 0)
GEMM_KERNEL(gemm_qk,   1, 0, 0, 1)   // bf16 scores, mask fused as residual
GEMM_KERNEL(gemm_av,   2, 0, 0, 0)
GEMM_KERNEL(gemm_ffn1, 1, 1, 1, 0)
GEMM_KERNEL(gemm_ffn2, 0, 0, 1, 1)

// ---------- row softmax over S, bf16 in (mask pre-added) -> bf16 out ----------
__global__ __launch_bounds__(256) void softmax_kernel(
    const unsigned short* __restrict__ Sb, unsigned short* __restrict__ Ab) {
  const long row = blockIdx.x;          // 0..MM-1
  const int tid = threadIdx.x;
  const unsigned short* sr = Sb + row * SS + tid * 8;
  bf16x8 sv = *(const bf16x8*)sr;
  float v[8];
  float mx = -1e30f;
#pragma unroll
  for (int i = 0; i < 8; ++i) {
    v[i] = b2f((unsigned short)sv[i]);
    mx = fmaxf(mx, v[i]);
  }
#pragma unroll
  for (int off = 32; off > 0; off >>= 1) mx = fmaxf(mx, __shfl_xor(mx, off, 64));
  __shared__ float rm[4], rs[4];
  if ((tid & 63) == 0) rm[tid >> 6] = mx;
  __syncthreads();
  mx = fmaxf(fmaxf(rm[0], rm[1]), fmaxf(rm[2], rm[3]));
  float sum = 0.f;
#pragma unroll
  for (int i = 0; i < 8; ++i) { v[i] = __expf(v[i] - mx); sum += v[i]; }
#pragma unroll
  for (int off = 32; off > 0; off >>= 1) sum += __shfl_xor(sum, off, 64);
  if ((tid & 63) == 0) rs[tid >> 6] = sum;
  __syncthreads();
  sum = rs[0] + rs[1] + rs[2] + rs[3];
  const float inv = 1.f / sum;
  bf16x8 ov;
#pragma unroll
  for (int i = 0; i < 8; ++i) ov[i] = (short)f2b(v[i] * inv);
  *(bf16x8*)(Ab + row * SS + tid * 8) = ov;
}

// ---------- in-place LayerNorm over H=1024 ----------
__global__ __launch_bounds__(256) void layernorm_kernel(
    float* __restrict__ Y, const float* __restrict__ g, const float* __restrict__ b) {
  const long row = blockIdx.x;
  float* y = Y + row * HH;
  const int tid = threadIdx.x;
  float v[4];
  float s = 0.f, ss = 0.f;
#pragma unroll
  for (int i = 0; i < 4; ++i) {
    v[i] = y[tid + i * 256];
    s += v[i]; ss += v[i] * v[i];
  }
#pragma unroll
  for (int off = 32; off > 0; off >>= 1) {
    s += __shfl_xor(s, off, 64);
    ss += __shfl_xor(ss, off, 64);
  }
  __shared__ float r1[4], r2[4];
  if ((tid & 63) == 0) { r1[tid >> 6] = s; r2[tid >> 6] = ss; }
  __syncthreads();
  s = r1[0] + r1[1] + r1[2] + r1[3];
  ss = r2[0] + r2[1] + r2[2] + r2[3];
  const float mu = s * (1.f / HH);
  const float var = ss * (1.f / HH) - mu * mu;
  const float rinv = rsqrtf(var + 1e-5f);
#pragma unroll
  for (int i = 0; i < 4; ++i) {
    int c = tid + i * 256;
    y[c] = (v[i] - mu) * rinv * g[c] + b[c];
  }
}

extern "C" void kernel_launch(void* const* d_in, const int* in_sizes, int n_in,
                              void* d_out, int out_size, void* d_ws, size_t ws_size,
                              hipStream_t stream) {
  (void)in_sizes; (void)n_in; (void)out_size; (void)ws_size;
  const float* x     = (const float*)d_in[0];
  const float* mask  = (const float*)d_in[1];
  const float* qW    = (const float*)d_in[2];
  const float* qb    = (const float*)d_in[3];
  const float* kW    = (const float*)d_in[4];
  const float* kb    = (const float*)d_in[5];
  const float* vW    = (const float*)d_in[6];
  const float* vb    = (const float*)d_in[7];
  const float* w1    = (const float*)d_in[8];
  const float* b1    = (const float*)d_in[9];
  const float* w2    = (const float*)d_in[10];
  const float* b2    = (const float*)d_in[11];
  const float* gamma = (const float*)d_in[12];
  const float* beta  = (const float*)d_in[13];
  float* out = (float*)d_out;

  char* ws = (char*)d_ws;
  size_t o = 0;
  auto alloc = [&](size_t bytes) { void* p = ws + o; o += (bytes + 255) & ~(size_t)255; return p; };
  unsigned short* Wqkv = (unsigned short*)alloc((size_t)3 * HH * HH * 2); // [3072][1024] (N,K) bf16
  unsigned short* w1t  = (unsigned short*)alloc((size_t)FF * HH * 2);     // [F][H]
  unsigned short* w2t  = (unsigned short*)alloc((size_t)HH * FF * 2);     // [H][F]
  float*          qkvb = (float*)alloc((size_t)3 * HH * 4);               // concat bias
  unsigned short* xb   = (unsigned short*)alloc((size_t)MM * HH * 2);     // x bf16
  unsigned short* QKVb = (unsigned short*)alloc((size_t)MM * 3 * HH * 2); // [M,3072] bf16
  unsigned short* Vt   = (unsigned short*)alloc((size_t)HH * MM * 2);     // [H][M] V^T bf16
  float*          attnf= (float*)alloc((size_t)MM * HH * 4);              // attn fp32 (residual)
  unsigned short* attnb= (unsigned short*)alloc((size_t)MM * HH * 2);     // attn bf16
  unsigned short* Sb   = (unsigned short*)alloc((size_t)BB * SS * SS * 4);// scores bf16 (over-alloc; tail reused as hb)
  unsigned short* Ab   = (unsigned short*)alloc((size_t)BB * SS * SS * 2);
  unsigned short* hb   = Sb + (size_t)BB * SS * SS;  // [M,F] bf16; Sb dead by FFN1 time

  const dim3 tb(32, 8);

  // 1. x -> bf16
  conv_f2b_kernel<<<MM * HH / 1024, 256, 0, stream>>>(x, xb, (long)MM * HH / 4);
  // 2. weight transposes (fp32 [K,N] -> bf16 [N,K]); QKV concatenated along N
  transpose_f2b_kernel<<<dim3(HH / 32, HH / 32), tb, 0, stream>>>(qW, Wqkv, HH, HH);
  transpose_f2b_kernel<<<dim3(HH / 32, HH / 32), tb, 0, stream>>>(kW, Wqkv + (size_t)HH * HH, HH, HH);
  transpose_f2b_kernel<<<dim3(HH / 32, HH / 32), tb, 0, stream>>>(vW, Wqkv + (size_t)2 * HH * HH, HH, HH);
  transpose_f2b_kernel<<<dim3(FF / 32, HH / 32), tb, 0, stream>>>(w1, w1t, HH, FF);
  transpose_f2b_kernel<<<dim3(HH / 32, FF / 32), tb, 0, stream>>>(w2, w2t, FF, HH);
  concat3_kernel<<<12, 256, 0, stream>>>(qb, kb, vb, qkvb);
  // 3. QKV = x * Wqkv^T + b, single GEMM, bf16 out [M,3072]
  gemm_qkv<<<dim3(3 * HH / 128, MM / 128, 1), 256, 0, stream>>>(
      xb, HH, 0, Wqkv, HH, 0, QKVb, 3 * HH, 0, nullptr, qkvb, nullptr, 0, 1.f, HH);
  // 4. V^T (bf16 [M,1024] slice of QKVb -> bf16 [1024,M])
  transpose_b2b_kernel<<<dim3(HH / 32, MM / 32), tb, 0, stream>>>(
      QKVb + 2 * HH, 3 * HH, Vt, MM, HH);
  // 5. S = Q K^T / sqrt(H) + mask, batched over BB, bf16 out
  gemm_qk<<<dim3(SS / 128, SS / 128, BB), 256, 0, stream>>>(
      QKVb, 3 * HH, (long)SS * 3 * HH, QKVb + HH, 3 * HH, (long)SS * 3 * HH,
      Sb, SS, (long)SS * SS, nullptr, nullptr, mask, SS, 0.03125f, HH);
  // 6. A = softmax(S) -> bf16
  softmax_kernel<<<MM, 256, 0, stream>>>(Sb, Ab);
  // 7. attn = A V, batched; fp32 + bf16 dual output
  gemm_av<<<dim3(HH / 128, SS / 128, BB), 256, 0, stream>>>(
      Ab, SS, (long)SS * SS, Vt, MM, SS, attnf, HH, (long)SS * HH,
      attnb, nullptr, nullptr, 0, 1.f, SS);
  // 8. h = relu(attn w1 + b1) -> bf16
  gemm_ffn1<<<dim3(FF / 128, MM / 128, 1), 256, 0, stream>>>(
      attnb, HH, 0, w1t, HH, 0, hb, FF, 0, nullptr, b1, nullptr, 0, 1.f, HH);
  // 9. y = attn + h w2 + b2 -> fp32 out
  gemm_ffn2<<<dim3(HH / 128, MM / 128, 1), 256, 0, stream>>>(
      hb, FF, 0, w2t, FF, 0, out, HH, 0, nullptr, b2, attnf, HH, 1.f, FF);
  // 10. LayerNorm in place
  layernorm_kernel<<<MM, 256, 0, stream>>>(out, gamma, beta);
}